// Round 10
// baseline (183.074 us; speedup 1.0000x reference)
//
#include <hip/hip_runtime.h>

// ---------------------------------------------------------------------------
// Multihead self-attention with RoPE, MI355X (gfx950).  Round 10.
// B=2, S=2048, H=16, DH=64, DM=1024.
// R10: (1) flash is L1-BW-bound on per-wave K/V redundancy (264 wave-ktiles
// x 16KB / 64B/cyc = 27.5us/CU). Fix: DUAL-QT waves -- block (bh,y) handles
// qtA=p, qtB=31-p in ONE merged k-loop; each K/V register load feeds both
// tiles' QK+PV. Beats=32-p; y->p map makes co-dispatched (y,y+8) sum to 49.
// (2) Q now frag-major (same layout as K) -> coalesced Q loads.
// (3) qkv 128x64 tiles (grid 1536 = 6/CU) and out_gemm 64x64 (1024 = 4/CU)
// for latency hiding; both were grid-starved at 3/2 blocks/CU.
// ---------------------------------------------------------------------------

typedef __attribute__((ext_vector_type(8))) short bf16x8;
typedef __attribute__((ext_vector_type(4))) float f32x4;

__device__ __forceinline__ short f2bf(float f) {
  unsigned u = __float_as_uint(f);
  unsigned r = (u + 0x7fffu + ((u >> 16) & 1u)) >> 16;   // RNE
  return (short)(r & 0xFFFFu);
}

// pack two f32 -> adjacent bf16 (round-half-up via +0x8000), one v_perm_b32
__device__ __forceinline__ unsigned pk2(float a, float b) {
  return __builtin_amdgcn_perm(__float_as_uint(b) + 0x8000u,
                               __float_as_uint(a) + 0x8000u, 0x07060302u);
}

// async global->LDS, 16B per lane. LDS dest must be wave-uniform base + lane*16.
__device__ __forceinline__ void async16(const void* g, void* l) {
  __builtin_amdgcn_global_load_lds(
      (const __attribute__((address_space(1))) void*)g,
      (__attribute__((address_space(3))) void*)l, 16, 0, 0);
}

__device__ __forceinline__ void cstore(short* C, size_t i, float v) { C[i] = f2bf(v); }
__device__ __forceinline__ void cstore(float* C, size_t i, float v) { C[i] = v; }

// ---------------------------------------------------------------------------
// merged f32 -> bf16 cast: X (1M float4) then Wq|Wk|Wv|Wo (dsts contiguous).
// ---------------------------------------------------------------------------
__global__ void cast_all(const float4* __restrict__ X,
                         const float4* __restrict__ w0, const float4* __restrict__ w1,
                         const float4* __restrict__ w2, const float4* __restrict__ w3,
                         short* __restrict__ Xb, short* __restrict__ Wb) {
  int t = blockIdx.x * 256 + threadIdx.x;
  const float4* s;
  short4* d;
  if (t < (1 << 20)) {
    s = X + t; d = (short4*)Xb + t;
  } else {
    int u = t - (1 << 20);
    int which = u >> 18;
    s = ((which == 0) ? w0 : (which == 1) ? w1 : (which == 2) ? w2 : w3) + (u & 0x3FFFF);
    d = (short4*)Wb + u;
  }
  float4 v = *s;
  *d = make_short4(f2bf(v.x), f2bf(v.y), f2bf(v.z), f2bf(v.w));
}

// ---------------------------------------------------------------------------
// bf16 GEMM core: C[M,N] = A[M,K] * B[N,K]^T, K=1024, lda=ldb=1024.
// BM=32*MR, BN=32*NR; 4 waves 2x2. LDS passed in. Double-buffered staging.
// Epilogue modes: EPI_ROW row-major; EPI_KFRAG / EPI_VFRAG fragment-major
// (per (b,h,kt,nb,half): 512-short segment in exact MFMA lane order).
// ---------------------------------------------------------------------------
enum EpiMode { EPI_ROW, EPI_KFRAG, EPI_VFRAG };

template <typename OUT, int MR, int NR, bool ROPE, EpiMode EM>
__device__ __forceinline__ void gemm_core(short* __restrict__ As, short* __restrict__ Bs,
                                          const short* __restrict__ A, const short* __restrict__ B,
                                          OUT* __restrict__ C, int bm, int bn, int ldc,
                                          const int* __restrict__ pos) {
  constexpr int BM = 32 * MR, BN = 32 * NR;
  const int tid  = threadIdx.x;
  const int lane = tid & 63, wave = tid >> 6;
  const int col  = lane & 15, quad = lane >> 4;
  const int wm = (wave & 1) * (16 * MR), wn = (wave >> 1) * (16 * NR);

  f32x4 acc[MR][NR];
#pragma unroll
  for (int i = 0; i < MR; i++)
#pragma unroll
    for (int j = 0; j < NR; j++) acc[i][j] = (f32x4){0.f, 0.f, 0.f, 0.f};

  auto stage = [&](int k0, int bu) {
#pragma unroll
    for (int c = tid; c < BM * 4; c += 256) {
      int r = c >> 2, cc = (c & 3) << 3;
      async16(A + (size_t)(bm + r) * 1024 + k0 + cc, As + bu * BM * 32 + c * 8);
    }
#pragma unroll
    for (int c = tid; c < BN * 4; c += 256) {
      int r = c >> 2, cc = (c & 3) << 3;
      async16(B + (size_t)(bn + r) * 1024 + k0 + cc, Bs + bu * BN * 32 + c * 8);
    }
  };

  stage(0, 0);
  for (int it = 0; it < 32; ++it) {
    __syncthreads();
    if (it < 31) stage((it + 1) * 32, (it + 1) & 1);
    const short* as = As + (it & 1) * BM * 32;
    const short* bs = Bs + (it & 1) * BN * 32;

    bf16x8 af[MR], bfr[NR];
#pragma unroll
    for (int i = 0; i < MR; i++)
      af[i] = *(const bf16x8*)(as + (wm + i * 16 + col) * 32 + quad * 8);
#pragma unroll
    for (int i = 0; i < NR; i++)
      bfr[i] = *(const bf16x8*)(bs + (wn + i * 16 + col) * 32 + quad * 8);
#pragma unroll
    for (int mi = 0; mi < MR; mi++)
#pragma unroll
      for (int ni = 0; ni < NR; ni++)
        acc[mi][ni] = __builtin_amdgcn_mfma_f32_16x16x32_bf16(af[mi], bfr[ni], acc[mi][ni], 0, 0, 0);
  }

  if (ROPE) {
    float invf_rev[NR];
#pragma unroll
    for (int ni = 0; ni < NR; ni++) {
      int pr = ((bn + wn + ni * 16 + col) & 63) >> 1;
      invf_rev[ni] = exp2f(-0.4152410118609203f * (float)pr) * 0.15915494309189535f;
    }
    const float sgn = (col & 1) ? 1.f : -1.f;
#pragma unroll
    for (int mi = 0; mi < MR; mi++) {
#pragma unroll
      for (int r = 0; r < 4; r++) {
        int row = bm + wm + mi * 16 + quad * 4 + r;
        float fp = (float)pos[row & 2047];
#pragma unroll
        for (int ni = 0; ni < NR; ni++) {
          float rev = fp * invf_rev[ni];
          rev -= floorf(rev);
          float sn = __builtin_amdgcn_sinf(rev);
          float cs = __builtin_amdgcn_cosf(rev);
          float x  = acc[mi][ni][r];
          float px = __shfl_xor(x, 1);
          acc[mi][ni][r] = fmaf(x, cs, sgn * px * sn);
        }
      }
    }
  }

  if (EM == EPI_ROW) {
#pragma unroll
    for (int mi = 0; mi < MR; mi++) {
#pragma unroll
      for (int r = 0; r < 4; r++) {
        size_t row = (size_t)(bm + wm + mi * 16 + quad * 4 + r);
#pragma unroll
        for (int ni = 0; ni < NR; ni++) {
          int cg = bn + wn + ni * 16 + col;
          cstore(C, row * ldc + cg, acc[mi][ni][r]);
        }
      }
    }
  } else if (EM == EPI_KFRAG) {
    // rows m = tokens, cols e = embed
#pragma unroll
    for (int mi = 0; mi < MR; mi++) {
#pragma unroll
      for (int r = 0; r < 4; r++) {
        int m = bm + wm + mi * 16 + quad * 4 + r;
        int bq = m >> 11, key = m & 2047;
        int kt = key >> 6, nb = (key >> 4) & 3, cl = key & 15;
#pragma unroll
        for (int ni = 0; ni < NR; ni++) {
          int e = bn + wn + ni * 16 + col;
          int h = e >> 6, d = e & 63;
          size_t seg = ((((size_t)(bq * 16 + h) * 32 + kt) * 4 + nb) * 2 + (d >> 5));
          cstore((short*)C, seg * 512 + (((d >> 3) & 3) * 16 + cl) * 8 + (d & 7), acc[mi][ni][r]);
        }
      }
    }
  } else {   // EPI_VFRAG: rows e = embed, cols m = tokens
#pragma unroll
    for (int mi = 0; mi < MR; mi++) {
#pragma unroll
      for (int r = 0; r < 4; r++) {
        int e = bm + wm + mi * 16 + quad * 4 + r;
        int h = e >> 6, d = e & 63;
        int nb = d >> 4, cl = d & 15;
#pragma unroll
        for (int ni = 0; ni < NR; ni++) {
          int m = bn + wn + ni * 16 + col;
          int bq = m >> 11, key = m & 2047;
          int kt = key >> 6, k64 = key & 63;
          size_t seg = ((((size_t)(bq * 16 + h) * 32 + kt) * 4 + nb) * 2 + (k64 >> 5));
          cstore((short*)C, seg * 512 + (((k64 >> 3) & 3) * 16 + cl) * 8 + (k64 & 7), acc[mi][ni][r]);
        }
      }
    }
  }
}

// z=0: Qf = rope(X Wq^T) frag-major; z=1: Kf = rope(X Wk^T) frag-major;
// z=2: Vf = Wv X^T frag-major.  Tiles 128x64, grid (32,16,3) = 1536 blocks.
__global__ __launch_bounds__(256) void qkv_gemm(const short* __restrict__ Xb,
                                                const short* __restrict__ Wq,
                                                const short* __restrict__ Wk,
                                                const short* __restrict__ Wv,
                                                short* __restrict__ Qf,
                                                short* __restrict__ Kf,
                                                short* __restrict__ Vf,
                                                const int* __restrict__ pos) {
  __shared__ __align__(16) short sm[2 * 128 * 32 + 2 * 64 * 32];   // 24 KB shared
  short* As = sm;
  short* Bs = sm + 2 * 128 * 32;
  const int z = blockIdx.z;
  const int x = blockIdx.x, y = blockIdx.y;
  if (z == 0)      gemm_core<short, 4, 2, true,  EPI_KFRAG>(As, Bs, Xb, Wq, Qf, x * 128, y * 64, 0, pos);
  else if (z == 1) gemm_core<short, 4, 2, true,  EPI_KFRAG>(As, Bs, Xb, Wk, Kf, x * 128, y * 64, 0, pos);
  else             gemm_core<short, 4, 2, false, EPI_VFRAG>(As, Bs, Wv, Xb, Vf,
                                                            (y >> 1) * 128, (x * 2 + (y & 1)) * 64, 0, pos);
}

__global__ __launch_bounds__(256) void out_gemm(const short* __restrict__ Ctx,
                                                const short* __restrict__ Wo,
                                                float* __restrict__ C) {
  __shared__ __align__(16) short sm[2 * 64 * 32 + 2 * 64 * 32];    // 16 KB
  gemm_core<float, 2, 2, false, EPI_ROW>(sm, sm + 2 * 64 * 32, Ctx, Wo, C,
                                         blockIdx.x * 64, blockIdx.y * 64, 1024, nullptr);
}

// ---------------------------------------------------------------------------
// Flash attention, causal, DUAL-QT waves. grid (bh=32, y=16). Block handles
// qtA = p, qtB = 31-p (p = y<8 ? y : 23-y) in ONE merged k-loop kt=0..qtB;
// A-side active while kt <= qtA. Each K/V register load feeds both tiles'
// QK and PV -> per-wave L1 traffic ~halved where shared. Beats = 32-p;
// co-dispatched blocks (y, y+8) sum to 49 beats per CU. 4 independent waves
// (no __syncthreads), wave = 16-q strip of each qt. Frag-major Q/K/V.
// LDS: 2 Ps slots per wave (xor-swizzled chunks, conflict-free) = 18 KB.
// ---------------------------------------------------------------------------
__global__ __launch_bounds__(256, 2) void flash_attn(const short* __restrict__ Qf,
                                                     const short* __restrict__ Kf,
                                                     const short* __restrict__ Vf,
                                                     short* __restrict__ ctx) {
  const int y = blockIdx.y;
  const int p = (y < 8) ? y : 23 - y;
  const int qtA = p, qtB = 31 - p;
  const int bh = blockIdx.x;
  const int b = bh >> 4, h = bh & 15;
  __shared__ __align__(16) short Ps[8][16 * 72];
  const int tid = threadIdx.x, lane = tid & 63, wave = tid >> 6;
  const int col = lane & 15, quad = lane >> 4;

  // fragment-major bases: bh covers 32 kt * 8 segs * 512 shorts = 131072
  const short* Kfb = Kf + (size_t)bh * 131072 + lane * 8;
  const short* Vfb = Vf + (size_t)bh * 131072 + lane * 8;
  const short* Qfb = Qf + (size_t)bh * 131072 + lane * 8 + wave * 1024;

  // Q fragments for both q-tiles (coalesced 1KB segment reads)
  bf16x8 qA0 = *(const bf16x8*)(Qfb + qtA * 4096);
  bf16x8 qA1 = *(const bf16x8*)(Qfb + qtA * 4096 + 512);
  bf16x8 qB0 = *(const bf16x8*)(Qfb + qtB * 4096);
  bf16x8 qB1 = *(const bf16x8*)(Qfb + qtB * 4096 + 512);

  float lA = 0.f, lB = 0.f;
  f32x4 oA[4], oB[4];
#pragma unroll
  for (int i = 0; i < 4; i++) { oA[i] = (f32x4){0.f, 0.f, 0.f, 0.f}; oB[i] = (f32x4){0.f, 0.f, 0.f, 0.f}; }

  const float C1 = 0.18033688011112042f;   // 0.125 * log2(e)
  const float C2 = 17.31234049066756f;     // 12 * log2(e)
  const int qgA = qtA * 64 + wave * 16 + col;
  const int qgB = qtB * 64 + wave * 16 + col;

  short* PsA = &Ps[wave * 2 + 0][0];
  short* PsB = &Ps[wave * 2 + 1][0];
  const int cx = col & 3;
  const int pswr0 = col * 72 + ((0 ^ cx) << 4) + quad * 4;
  const int pswr1 = col * 72 + ((1 ^ cx) << 4) + quad * 4;
  const int pswr2 = col * 72 + ((2 ^ cx) << 4) + quad * 4;
  const int pswr3 = col * 72 + ((3 ^ cx) << 4) + quad * 4;
  const int psrd0 = col * 72 + (((quad >> 1) ^ cx) << 4) + (quad & 1) * 8;
  const int psrd1 = col * 72 + ((((quad >> 1) + 2) ^ cx) << 4) + (quad & 1) * 8;

  auto ldk = [&](int kt, bf16x8 (&kf)[4][2]) {
    const int base = kt * 4096;
#pragma unroll
    for (int nb = 0; nb < 4; nb++) {
      kf[nb][0] = *(const bf16x8*)(Kfb + base + (nb * 2 + 0) * 512);
      kf[nb][1] = *(const bf16x8*)(Kfb + base + (nb * 2 + 1) * 512);
    }
  };
  auto ldv = [&](int kt, bf16x8 (&vf)[4][2]) {
    const int base = kt * 4096;
#pragma unroll
    for (int nb = 0; nb < 4; nb++) {
      vf[nb][0] = *(const bf16x8*)(Vfb + base + (nb * 2 + 0) * 512);
      vf[nb][1] = *(const bf16x8*)(Vfb + base + (nb * 2 + 1) * 512);
    }
  };

  bf16x8 kf[4][2], vf[4][2];
  ldk(0, kf);

  for (int kt = 0; kt <= qtB; ++kt) {
    // V for this tile: issued now, consumed at PV (QK+softmax hides)
    ldv(kt, vf);
    // S^T for B (always active); kf was prefetched last iteration
    f32x4 sB[4];
#pragma unroll
    for (int nb = 0; nb < 4; nb++) {
      f32x4 z = (f32x4){0.f, 0.f, 0.f, 0.f};
      z = __builtin_amdgcn_mfma_f32_16x16x32_bf16(kf[nb][0], qB0, z, 0, 0, 0);
      z = __builtin_amdgcn_mfma_f32_16x16x32_bf16(kf[nb][1], qB1, z, 0, 0, 0);
      sB[nb] = z;
    }
    // S^T for A while active -- reuses the SAME kf registers (free L1-wise)
    const bool aAct = (kt <= qtA);
    f32x4 sA[4];
    if (aAct) {
#pragma unroll
      for (int nb = 0; nb < 4; nb++) {
        f32x4 z = (f32x4){0.f, 0.f, 0.f, 0.f};
        z = __builtin_amdgcn_mfma_f32_16x16x32_bf16(kf[nb][0], qA0, z, 0, 0, 0);
        z = __builtin_amdgcn_mfma_f32_16x16x32_bf16(kf[nb][1], qA1, z, 0, 0, 0);
        sA[nb] = z;
      }
    }
    // prefetch next K (kf dead now)
    if (kt < qtB) ldk(kt + 1, kf);

    // ---- B: softmax + pack + PV ----
    {
      const bool diag = (kt == qtB);
#pragma unroll
      for (int nb = 0; nb < 4; nb++) {
        float pv[4];
#pragma unroll
        for (int r = 0; r < 4; r++) {
          pv[r] = exp2f(sB[nb][r] * C1 - C2);
          if (diag && (kt * 64 + nb * 16 + quad * 4 + r) > qgB) pv[r] = 0.f;
          lB += pv[r];
        }
        int wr = (nb == 0) ? pswr0 : (nb == 1) ? pswr1 : (nb == 2) ? pswr2 : pswr3;
        *(uint2*)(PsB + wr) = make_uint2(pk2(pv[0], pv[1]), pk2(pv[2], pv[3]));
      }
      bf16x8 af0 = *(const bf16x8*)(PsB + psrd0);
      bf16x8 af1 = *(const bf16x8*)(PsB + psrd1);
#pragma unroll
      for (int nb = 0; nb < 4; nb++) {
        oB[nb] = __builtin_amdgcn_mfma_f32_16x16x32_bf16(af0, vf[nb][0], oB[nb], 0, 0, 0);
        oB[nb] = __builtin_amdgcn_mfma_f32_16x16x32_bf16(af1, vf[nb][1], oB[nb], 0, 0, 0);
      }
    }
    // ---- A: softmax + pack + PV (same vf registers) ----
    if (aAct) {
      const bool diag = (kt == qtA);
#pragma unroll
      for (int nb = 0; nb < 4; nb++) {
        float pv[4];
#pragma unroll
        for (int r = 0; r < 4; r++) {
          pv[r] = exp2f(sA[nb][r] * C1 - C2);
          if (diag && (kt * 64 + nb * 16 + quad * 4 + r) > qgA) pv[r] = 0.f;
          lA += pv[r];
        }
        int wr = (nb == 0) ? pswr0 : (nb == 1) ? pswr1 : (nb == 2) ? pswr2 : pswr3;
        *(uint2*)(PsA + wr) = make_uint2(pk2(pv[0], pv[1]), pk2(pv[2], pv[3]));
      }
      bf16x8 af0 = *(const bf16x8*)(PsA + psrd0);
      bf16x8 af1 = *(const bf16x8*)(PsA + psrd1);
#pragma unroll
      for (int nb = 0; nb < 4; nb++) {
        oA[nb] = __builtin_amdgcn_mfma_f32_16x16x32_bf16(af0, vf[nb][0], oA[nb], 0, 0, 0);
        oA[nb] = __builtin_amdgcn_mfma_f32_16x16x32_bf16(af1, vf[nb][1], oA[nb], 0, 0, 0);
      }
    }
  }

  // epilogues: l reduction over the 4 quads sharing this col, then writes
  lA += __shfl_xor(lA, 16);  lA += __shfl_xor(lA, 32);
  lB += __shfl_xor(lB, 16);  lB += __shfl_xor(lB, 32);
  float invA = 1.0f / lA, invB = 1.0f / lB;

#pragma unroll
  for (int r = 0; r < 4; r++) {
    float ia = __shfl(invA, quad * 4 + r);
    float ib = __shfl(invB, quad * 4 + r);
    size_t rowA = (size_t)(b * 2048 + qtA * 64 + wave * 16 + quad * 4 + r);
    size_t rowB = (size_t)(b * 2048 + qtB * 64 + wave * 16 + quad * 4 + r);
#pragma unroll
    for (int nb = 0; nb < 4; nb++) {
      ctx[rowA * 1024 + h * 64 + nb * 16 + col] = f2bf(oA[nb][r] * ia);
      ctx[rowB * 1024 + h * 64 + nb * 16 + col] = f2bf(oB[nb][r] * ib);
    }
  }
}

// ---------------------------------------------------------------------------
extern "C" void kernel_launch(void* const* d_in, const int* in_sizes, int n_in,
                              void* d_out, int out_size, void* d_ws, size_t ws_size,
                              hipStream_t stream) {
  const float* X  = (const float*)d_in[0];
  const int* pos  = (const int*)d_in[1];
  const float* wq = (const float*)d_in[2];
  const float* wk = (const float*)d_in[3];
  const float* wv = (const float*)d_in[4];
  const float* wo = (const float*)d_in[5];
  float* out = (float*)d_out;

  short* Xb  = (short*)d_ws;
  short* Wqb = Xb + (1 << 22);
  short* Wkb = Wqb + (1 << 20);
  short* Wvb = Wkb + (1 << 20);
  short* Wob = Wvb + (1 << 20);
  short* Qfb = Wob + (1 << 20);
  short* Kfb = Qfb + (1 << 22);
  short* Vfb = Kfb + (1 << 22);
  short* Ctx = Vfb + (1 << 22);

  cast_all<<<8192, 256, 0, stream>>>((const float4*)X, (const float4*)wq, (const float4*)wk,
                                     (const float4*)wv, (const float4*)wo, Xb, Wqb);
  qkv_gemm<<<dim3(32, 16, 3), 256, 0, stream>>>(Xb, Wqb, Wkb, Wvb, Qfb, Kfb, Vfb, pos);
  flash_attn<<<dim3(32, 16), 256, 0, stream>>>(Qfb, Kfb, Vfb, Ctx);
  out_gemm<<<dim3(64, 16), 256, 0, stream>>>(Ctx, Wob, out);
}